// Round 6
// baseline (868.114 us; speedup 1.0000x reference)
//
#include <hip/hip_runtime.h>
#include <hip/hip_bf16.h>
#include <math.h>

typedef __bf16 bf16x8 __attribute__((ext_vector_type(8)));
typedef float  f32x4  __attribute__((ext_vector_type(4)));
typedef unsigned int u32x4 __attribute__((ext_vector_type(4)));
typedef __hip_bfloat16 bf16_t;

static constexpr int C_    = 128;
static constexpr int L_    = 56 * 56;        // tokens per image
static constexpr int M_    = 64 * L_;        // 200704 total tokens
static constexpr int NWIN  = 64 * 64;        // 4096 windows
static constexpr int VSTR  = 56;             // vT padded key stride

// map windowed token index tw -> unwindowed token index (shift+window bijection)
__device__ inline long win_to_tok(int tw)
{
    int win = tw / 49, n = tw % 49;
    int bb  = win >> 6, wi = win & 63;
    int wh  = wi >> 3, wwp = wi & 7;
    int hs  = wh * 7 + n / 7;
    int wsv = wwp * 7 + n % 7;
    int hh  = (hs + 3) % 56;          // un-shift
    int ww  = (wsv + 3) % 56;
    return (long)bb * L_ + hh * 56 + ww;
}

__device__ inline unsigned int pk2(float lo, float hi)
{
    unsigned short a = __builtin_bit_cast(unsigned short, (__bf16)lo);
    unsigned short b = __builtin_bit_cast(unsigned short, (__bf16)hi);
    return (unsigned int)a | ((unsigned int)b << 16);
}

__global__ void sentinel_kernel(float* o) { o[threadIdx.x] = 1e9f; }

// ---------------------------------------------------------------------------
__global__ void transpose_w(const float* __restrict__ w, bf16_t* __restrict__ wt,
                            int K, int N)
{
    int i = blockIdx.x * 256 + threadIdx.x;
    if (i >= K * N) return;
    int k = i / N, n = i % N;
    wt[(long)n * K + k] = __float2bfloat16(w[i]);
}

// zero vT pad keys 49..55 for all (win, d)
__global__ void zpad_kernel(bf16_t* __restrict__ vT)
{
    long i = (long)blockIdx.x * 256 + threadIdx.x;
    if (i >= (long)NWIN * 128 * 7) return;
    long row = i / 7;
    int  k   = 49 + (int)(i % 7);
    vT[row * VSTR + k] = __float2bfloat16(0.f);
}

// ---------------------------------------------------------------------------
// GEMM, one wave = 64x64 output tile. Block = 4 waves stacked in M (256 rows).
// grid = (M/256, N/64).
// LNM: 0 = A is plain bf16 row-major
//      1 = A = LN1(gather shifted/windowed row of x f32)   [qkv]
// EPI: 0 = qkv: cols<256 -> qk[token][256]; cols>=256 -> vT[win][d][key]
//      1 = proj: window-reverse + unshift + x(f32) residual -> f32 out
// ---------------------------------------------------------------------------
template<int K, int N, int LNM, int EPI>
__global__ __launch_bounds__(256) void gemm2(const void*  __restrict__ Asrc,
                                             const float* __restrict__ lng,
                                             const float* __restrict__ lnb,
                                             const bf16_t* __restrict__ Bt,
                                             const float*  __restrict__ bias,
                                             void*         outp,
                                             const float*  resf,
                                             bf16_t*       vTp)
{
    int lane = threadIdx.x & 63;
    int wave = threadIdx.x >> 6;
    int la = lane & 15, lb = lane >> 4;
    int m0   = (blockIdx.x * 4 + wave) * 64;
    int c0   = blockIdx.y * 64;

    f32x4 acc[4][4];
#pragma unroll
    for (int nt = 0; nt < 4; ++nt) {
        float bv = bias[c0 + nt * 16 + la];
#pragma unroll
        for (int s = 0; s < 4; ++s) acc[s][nt] = (f32x4){bv, bv, bv, bv};
    }

    static_assert(K == 128, "gemm2 is K=128 only now");
    bf16x8 areg[4][4];
    if constexpr (LNM == 0) {
#pragma unroll
        for (int s = 0; s < 4; ++s)
#pragma unroll
            for (int kt = 0; kt < 4; ++kt)
                areg[s][kt] = *reinterpret_cast<const bf16x8*>(
                    (const bf16_t*)Asrc + (long)(m0 + s * 16 + la) * K + kt * 32 + lb * 8);
    } else {
#pragma unroll
        for (int s = 0; s < 4; ++s) {
            long src = win_to_tok(m0 + s * 16 + la);
            const float* xr = (const float*)Asrc + src * C_;
            float vals[4][8];
            float sm = 0.f, qs = 0.f;
#pragma unroll
            for (int kt = 0; kt < 4; ++kt) {
                f32x4 u0 = *reinterpret_cast<const f32x4*>(xr + kt * 32 + lb * 8);
                f32x4 u1 = *reinterpret_cast<const f32x4*>(xr + kt * 32 + lb * 8 + 4);
#pragma unroll
                for (int j = 0; j < 4; ++j) { vals[kt][j] = u0[j]; vals[kt][4 + j] = u1[j]; }
#pragma unroll
                for (int j = 0; j < 8; ++j) { sm += vals[kt][j]; qs += vals[kt][j] * vals[kt][j]; }
            }
            sm += __shfl_xor(sm, 16); sm += __shfl_xor(sm, 32);
            qs += __shfl_xor(qs, 16); qs += __shfl_xor(qs, 32);
            float mean = sm * (1.f / 128.f);
            float rstd = rsqrtf(qs * (1.f / 128.f) - mean * mean + 1e-5f);
#pragma unroll
            for (int kt = 0; kt < 4; ++kt)
#pragma unroll
                for (int j = 0; j < 8; ++j) {
                    int col = kt * 32 + lb * 8 + j;
                    areg[s][kt][j] = (__bf16)((vals[kt][j] - mean) * rstd * lng[col] + lnb[col]);
                }
        }
    }

    bf16x8 breg[4][4];
#pragma unroll
    for (int kt = 0; kt < 4; ++kt)
#pragma unroll
        for (int nt = 0; nt < 4; ++nt)
            breg[kt][nt] = *reinterpret_cast<const bf16x8*>(
                Bt + (long)(c0 + nt * 16 + la) * K + kt * 32 + lb * 8);
#pragma unroll
    for (int kt = 0; kt < 4; ++kt)
#pragma unroll
        for (int nt = 0; nt < 4; ++nt)
#pragma unroll
            for (int s = 0; s < 4; ++s)
                acc[s][nt] = __builtin_amdgcn_mfma_f32_16x16x32_bf16(
                    areg[s][kt], breg[kt][nt], acc[s][nt], 0, 0, 0);

#pragma unroll
    for (int s = 0; s < 4; ++s) {
#pragma unroll
        for (int r = 0; r < 4; ++r) {
            int row = m0 + s * 16 + lb * 4 + r;
            if constexpr (EPI == 0) {
                int win = row / 49, key = row - win * 49;
#pragma unroll
                for (int nt = 0; nt < 4; ++nt) {
                    int col = c0 + nt * 16 + la;
                    float v = acc[s][nt][r];
                    if (col < 256)
                        ((bf16_t*)outp)[(long)row * 256 + col] = __float2bfloat16(v);
                    else
                        vTp[((long)win * 128 + (col - 256)) * VSTR + key] = __float2bfloat16(v);
                }
            } else {
                long to = win_to_tok(row);
#pragma unroll
                for (int nt = 0; nt < 4; ++nt) {
                    int col = c0 + nt * 16 + la;
                    ((float*)outp)[to * C_ + col] = acc[s][nt][r] + resf[to * C_ + col];
                }
            }
        }
    }
}

// ---------------------------------------------------------------------------
// MFMA windowed attention: one block per window, one wave per head. No LDS.
// ---------------------------------------------------------------------------
__global__ __launch_bounds__(256) void attn_mfma(const bf16_t* __restrict__ qk,
                                                 const bf16_t* __restrict__ vT,
                                                 const float*  __restrict__ rpb,
                                                 bf16_t* __restrict__ out)
{
    int win  = blockIdx.x;
    int h    = threadIdx.x >> 6;
    int lane = threadIdx.x & 63;
    int la = lane & 15, lb = lane >> 4;

    const bf16_t* qkw = qk + (long)win * 49 * 256;

    bf16x8 kf[4], qf[4];
#pragma unroll
    for (int t = 0; t < 4; ++t) {
        kf[t] = *reinterpret_cast<const bf16x8*>(qkw + (long)(t * 16 + la) * 256 + 128 + h * 32 + lb * 8);
        qf[t] = *reinterpret_cast<const bf16x8*>(qkw + (long)(t * 16 + la) * 256 +       h * 32 + lb * 8);
    }

    f32x4 S[4][4];
#pragma unroll
    for (int qt = 0; qt < 4; ++qt)
#pragma unroll
        for (int kt = 0; kt < 4; ++kt)
            S[qt][kt] = __builtin_amdgcn_mfma_f32_16x16x32_bf16(
                kf[kt], qf[qt], (f32x4){0.f, 0.f, 0.f, 0.f}, 0, 0, 0);

    const float scale = 0.17677669529663687f;   // 1/sqrt(32)
    int wi  = win & 63;
    int wh  = wi >> 3, wwp = wi & 7;
    bool edge = (wh == 7) || (wwp == 7);

    int i1[4], j1[4], r1[4], c1[4];
#pragma unroll
    for (int qt = 0; qt < 4; ++qt) {
        int q  = qt * 16 + la;
        int qc = q < 49 ? q : 48;
        i1[qt] = qc / 7; j1[qt] = qc - 7 * i1[qt];
        r1[qt] = (wh  < 7) ? 0 : ((i1[qt] < 4) ? 1 : 2);
        c1[qt] = (wwp < 7) ? 0 : ((j1[qt] < 4) ? 1 : 2);
    }

#pragma unroll
    for (int kt = 0; kt < 4; ++kt) {
#pragma unroll
        for (int r = 0; r < 4; ++r) {
            if (kt == 3 && r > 0) {
#pragma unroll
                for (int qt = 0; qt < 4; ++qt) S[qt][kt][r] = -1e30f;
                continue;
            }
            int key = kt * 16 + lb * 4 + r;
            int kc  = key < 49 ? key : 48;
            int i2  = kc / 7, j2 = kc - 7 * i2;
            int r2  = (wh  < 7) ? 0 : ((i2 < 4) ? 1 : 2);
            int c2  = (wwp < 7) ? 0 : ((j2 < 4) ? 1 : 2);
#pragma unroll
            for (int qt = 0; qt < 4; ++qt) {
                float bv  = rpb[(((i1[qt] - i2 + 6) * 13 + (j1[qt] - j2 + 6)) << 2) + h];
                float val = S[qt][kt][r] * scale + bv;
                if (edge && ((r1[qt] != r2) | (c1[qt] != c2))) val -= 100.f;
                if (kt == 3 && lb > 0) val = -1e30f;
                S[qt][kt][r] = val;
            }
        }
    }

    float inv[4];
#pragma unroll
    for (int qt = 0; qt < 4; ++qt) {
        float mx = -3e38f;
#pragma unroll
        for (int kt = 0; kt < 4; ++kt)
#pragma unroll
            for (int r = 0; r < 4; ++r) mx = fmaxf(mx, S[qt][kt][r]);
        mx = fmaxf(mx, __shfl_xor(mx, 16));
        mx = fmaxf(mx, __shfl_xor(mx, 32));
        float sm = 0.f;
#pragma unroll
        for (int kt = 0; kt < 4; ++kt)
#pragma unroll
            for (int r = 0; r < 4; ++r) {
                float e = __expf(S[qt][kt][r] - mx);
                S[qt][kt][r] = e;
                sm += e;
            }
        sm += __shfl_xor(sm, 16);
        sm += __shfl_xor(sm, 32);
        inv[qt] = 1.f / sm;
    }

    unsigned int w_[4][4][2];
#pragma unroll
    for (int qt = 0; qt < 4; ++qt)
#pragma unroll
        for (int t = 0; t < 4; ++t) {
            w_[qt][t][0] = pk2(S[qt][t][0], S[qt][t][1]);
            w_[qt][t][1] = pk2(S[qt][t][2], S[qt][t][3]);
        }

    int srcA = la + (((2 * lb)     & 3) << 4);
    int srcB = la + (((2 * lb + 1) & 3) << 4);
    bool hiT = (lb >> 1) & 1;

    f32x4 O[2][4];
#pragma unroll
    for (int dt = 0; dt < 2; ++dt)
#pragma unroll
        for (int qt = 0; qt < 4; ++qt) O[dt][qt] = (f32x4){0.f, 0.f, 0.f, 0.f};

    const bf16_t* vrow = vT + ((long)win * 128 + h * 32) * VSTR;
#pragma unroll
    for (int kk = 0; kk < 2; ++kk) {
        bf16x8 vf[2];
#pragma unroll
        for (int dt = 0; dt < 2; ++dt)
            vf[dt] = *reinterpret_cast<const bf16x8*>(
                vrow + (long)(dt * 16 + la) * VSTR + kk * 32 + lb * 8);
        int tl = kk * 2;
#pragma unroll
        for (int qt = 0; qt < 4; ++qt) {
            unsigned int a0 = __shfl(w_[qt][tl][0],     srcA);
            unsigned int b0 = __shfl(w_[qt][tl + 1][0], srcA);
            unsigned int a1 = __shfl(w_[qt][tl][1],     srcA);
            unsigned int b1 = __shfl(w_[qt][tl + 1][1], srcA);
            unsigned int a2 = __shfl(w_[qt][tl][0],     srcB);
            unsigned int b2 = __shfl(w_[qt][tl + 1][0], srcB);
            unsigned int a3 = __shfl(w_[qt][tl][1],     srcB);
            unsigned int b3 = __shfl(w_[qt][tl + 1][1], srcB);
            u32x4 uu = { hiT ? b0 : a0, hiT ? b1 : a1, hiT ? b2 : a2, hiT ? b3 : a3 };
            bf16x8 pf = __builtin_bit_cast(bf16x8, uu);
#pragma unroll
            for (int dt = 0; dt < 2; ++dt)
                O[dt][qt] = __builtin_amdgcn_mfma_f32_16x16x32_bf16(vf[dt], pf, O[dt][qt], 0, 0, 0);
        }
    }

    bf16_t* ob = out + (long)win * 49 * C_ + h * 32;
#pragma unroll
    for (int qt = 0; qt < 4; ++qt) {
        int q = qt * 16 + la;
        if (q < 49) {
            float iv = inv[qt];
#pragma unroll
            for (int dt = 0; dt < 2; ++dt) {
                unsigned int s0 = pk2(O[dt][qt][0] * iv, O[dt][qt][1] * iv);
                unsigned int s1 = pk2(O[dt][qt][2] * iv, O[dt][qt][3] * iv);
                uint2 st = {s0, s1};
                *reinterpret_cast<uint2*>(ob + (long)q * C_ + dt * 16 + lb * 4) = st;
            }
        }
    }
}

// ---------------------------------------------------------------------------
// Fused MLP: out = y + fc2(gelu(fc1(LN2(y)))).  One wave = 16 rows.
// Block = 4 waves = 64 rows; grid = M/64. Hidden (512) in 8 chunks of 64.
// h transposed to A-fragments via per-wave double-buffered LDS tile.
// ---------------------------------------------------------------------------
__global__ __launch_bounds__(256) void mlp_fused(const float* __restrict__ y,
                                                 const float* __restrict__ g,
                                                 const float* __restrict__ b,
                                                 const bf16_t* __restrict__ w1t,
                                                 const float* __restrict__ b1,
                                                 const bf16_t* __restrict__ w2t,
                                                 const float* __restrict__ b2,
                                                 float* __restrict__ out)
{
    int lane = threadIdx.x & 63;
    int wave = threadIdx.x >> 6;
    int la = lane & 15, lb = lane >> 4;
    int m0 = blockIdx.x * 64 + wave * 16;

    __shared__ __bf16 hl[2][4][16][72];      // double-buffered per-wave h tile

    // ---- LN2 of row (m0+la) ----
    const float* yr = y + (long)(m0 + la) * C_;
    float v[4][8];
    float sm = 0.f, qs = 0.f;
#pragma unroll
    for (int kt = 0; kt < 4; ++kt) {
        f32x4 u0 = *reinterpret_cast<const f32x4*>(yr + kt * 32 + lb * 8);
        f32x4 u1 = *reinterpret_cast<const f32x4*>(yr + kt * 32 + lb * 8 + 4);
#pragma unroll
        for (int j = 0; j < 4; ++j) { v[kt][j] = u0[j]; v[kt][4 + j] = u1[j]; }
#pragma unroll
        for (int j = 0; j < 8; ++j) { sm += v[kt][j]; qs += v[kt][j] * v[kt][j]; }
    }
    sm += __shfl_xor(sm, 16); sm += __shfl_xor(sm, 32);
    qs += __shfl_xor(qs, 16); qs += __shfl_xor(qs, 32);
    float mean = sm * (1.f / 128.f);
    float rstd = rsqrtf(qs * (1.f / 128.f) - mean * mean + 1e-5f);
    bf16x8 af[4];
#pragma unroll
    for (int kt = 0; kt < 4; ++kt)
#pragma unroll
        for (int j = 0; j < 8; ++j) {
            int col = kt * 32 + lb * 8 + j;
            af[kt][j] = (__bf16)((v[kt][j] - mean) * rstd * g[col] + b[col]);
        }

    // ---- output accumulators (16 rows x 128 cols) ----
    f32x4 acc[8];
#pragma unroll
    for (int nt = 0; nt < 8; ++nt) {
        float bv = b2[nt * 16 + la];
        acc[nt] = (f32x4){bv, bv, bv, bv};
    }

    // ---- hidden chunks ----
    for (int c = 0; c < 8; ++c) {
        int p = c & 1;
        f32x4 hacc[4];
#pragma unroll
        for (int nt = 0; nt < 4; ++nt) {
            float bv = b1[c * 64 + nt * 16 + la];
            hacc[nt] = (f32x4){bv, bv, bv, bv};
        }
#pragma unroll
        for (int kt = 0; kt < 4; ++kt)
#pragma unroll
            for (int nt = 0; nt < 4; ++nt) {
                bf16x8 w1f = *reinterpret_cast<const bf16x8*>(
                    w1t + (long)(c * 64 + nt * 16 + la) * 128 + kt * 32 + lb * 8);
                hacc[nt] = __builtin_amdgcn_mfma_f32_16x16x32_bf16(af[kt], w1f, hacc[nt], 0, 0, 0);
            }
        // GELU (exact) -> LDS (transpose to A-frag layout)
#pragma unroll
        for (int nt = 0; nt < 4; ++nt)
#pragma unroll
            for (int r = 0; r < 4; ++r) {
                float hv = hacc[nt][r];
                hv = 0.5f * hv * (1.f + erff(hv * 0.70710678118654752f));
                hl[p][wave][lb * 4 + r][nt * 16 + la] = (__bf16)hv;
            }
        __syncthreads();
        bf16x8 hf0 = *reinterpret_cast<const bf16x8*>(&hl[p][wave][la][lb * 8]);
        bf16x8 hf1 = *reinterpret_cast<const bf16x8*>(&hl[p][wave][la][32 + lb * 8]);
#pragma unroll
        for (int nt = 0; nt < 8; ++nt) {
            bf16x8 w2f0 = *reinterpret_cast<const bf16x8*>(
                w2t + (long)(nt * 16 + la) * 512 + c * 64 + lb * 8);
            bf16x8 w2f1 = *reinterpret_cast<const bf16x8*>(
                w2t + (long)(nt * 16 + la) * 512 + c * 64 + 32 + lb * 8);
            acc[nt] = __builtin_amdgcn_mfma_f32_16x16x32_bf16(hf0, w2f0, acc[nt], 0, 0, 0);
            acc[nt] = __builtin_amdgcn_mfma_f32_16x16x32_bf16(hf1, w2f1, acc[nt], 0, 0, 0);
        }
    }

    // ---- epilogue: + y residual -> out (f32), rows m0+lb*4+r ----
#pragma unroll
    for (int r = 0; r < 4; ++r) {
        long row = m0 + lb * 4 + r;
#pragma unroll
        for (int nt = 0; nt < 8; ++nt) {
            int col = nt * 16 + la;
            out[row * C_ + col] = acc[nt][r] + y[row * C_ + col];
        }
    }
}

// ---------------------------------------------------------------------------
extern "C" void kernel_launch(void* const* d_in, const int* in_sizes, int n_in,
                              void* d_out, int out_size, void* d_ws, size_t ws_size,
                              hipStream_t stream)
{
    (void)in_sizes; (void)n_in; (void)out_size;

    const float* x      = (const float*)d_in[0];
    const float* n1g    = (const float*)d_in[1];
    const float* n1b    = (const float*)d_in[2];
    const float* qkv_w  = (const float*)d_in[3];
    const float* qkv_b  = (const float*)d_in[4];
    const float* proj_w = (const float*)d_in[5];
    const float* proj_b = (const float*)d_in[6];
    const float* rpb    = (const float*)d_in[7];
    const float* n2g    = (const float*)d_in[8];
    const float* n2b    = (const float*)d_in[9];
    const float* fc1_w  = (const float*)d_in[10];
    const float* fc1_b  = (const float*)d_in[11];
    const float* fc2_w  = (const float*)d_in[12];
    const float* fc2_b  = (const float*)d_in[13];

    char* ws = (char*)d_ws;

    const size_t qk_sz = (size_t)M_ * 256 * 2;               // 102,760,448
    const size_t vt_sz = (size_t)NWIN * 128 * VSTR * 2;      //  58,720,256
    const size_t at_sz = (size_t)M_ * 128 * 2;               //  51,380,224
    const size_t w_off = qk_sz + vt_sz + at_sz;
    const size_t w_sz  = (size_t)(128 * 384 + 128 * 128 + 128 * 512 + 512 * 128) * 2;
    const size_t need  = w_off + w_sz;                       // ~213.6 MB

    if (need > ws_size) {
        sentinel_kernel<<<1, 256, 0, stream>>>((float*)d_out);
        return;
    }

    bf16_t* qkb  = (bf16_t*)ws;
    bf16_t* vT   = (bf16_t*)(ws + qk_sz);
    bf16_t* attb = (bf16_t*)(ws + qk_sz + vt_sz);
    bf16_t* qkv_wt  = (bf16_t*)(ws + w_off);
    bf16_t* proj_wt = qkv_wt + 128 * 384;
    bf16_t* fc1_wt  = proj_wt + 128 * 128;
    bf16_t* fc2_wt  = fc1_wt + 128 * 512;

    float* y = (float*)d_out;

    transpose_w<<<(128 * 384 + 255) / 256, 256, 0, stream>>>(qkv_w, qkv_wt, 128, 384);
    transpose_w<<<(128 * 128 + 255) / 256, 256, 0, stream>>>(proj_w, proj_wt, 128, 128);
    transpose_w<<<(128 * 512 + 255) / 256, 256, 0, stream>>>(fc1_w, fc1_wt, 128, 512);
    transpose_w<<<(512 * 128 + 255) / 256, 256, 0, stream>>>(fc2_w, fc2_wt, 512, 128);

    // zero vT pad keys (NaN safety for PV fragments)
    zpad_kernel<<<(NWIN * 128 * 7 + 255) / 256, 256, 0, stream>>>(vT);
    // LN1 + shift/window gather fused into QKV projection
    gemm2<128, 384, 1, 0><<<dim3(M_ / 256, 6), 256, 0, stream>>>(
        x, n1g, n1b, qkv_wt, qkv_b, qkb, nullptr, vT);
    // MFMA attention
    attn_mfma<<<NWIN, 256, 0, stream>>>(qkb, vT, rpb, attb);
    // proj + window-reverse + x residual -> f32 y (= d_out)
    gemm2<128, 128, 0, 1><<<dim3(M_ / 256, 2), 256, 0, stream>>>(
        attb, nullptr, nullptr, proj_wt, proj_b, y, x, nullptr);
    // fused LN2 + fc1 + GELU + fc2 + residual (in-place on d_out)
    mlp_fused<<<M_ / 64, 256, 0, stream>>>(
        y, n2g, n2b, fc1_wt, fc1_b, fc2_wt, fc2_b, y);
}

// Round 8
// 749.907 us; speedup vs baseline: 1.1576x; 1.1576x over previous
//
#include <hip/hip_runtime.h>
#include <hip/hip_bf16.h>
#include <math.h>

typedef __bf16 bf16x8 __attribute__((ext_vector_type(8)));
typedef float  f32x4  __attribute__((ext_vector_type(4)));
typedef unsigned int u32x4 __attribute__((ext_vector_type(4)));
typedef __hip_bfloat16 bf16_t;

static constexpr int C_    = 128;
static constexpr int L_    = 56 * 56;        // tokens per image
static constexpr int M_    = 64 * L_;        // 200704 total tokens
static constexpr int NWIN  = 64 * 64;        // 4096 windows
static constexpr int VSTR  = 56;             // vT padded key stride

// map windowed token index tw -> unwindowed token index (shift+window bijection)
__device__ inline long win_to_tok(int tw)
{
    int win = tw / 49, n = tw % 49;
    int bb  = win >> 6, wi = win & 63;
    int wh  = wi >> 3, wwp = wi & 7;
    int hs  = wh * 7 + n / 7;
    int wsv = wwp * 7 + n % 7;
    int hh  = (hs + 3) % 56;          // un-shift
    int ww  = (wsv + 3) % 56;
    return (long)bb * L_ + hh * 56 + ww;
}

__device__ inline unsigned int pk2(float lo, float hi)
{
    unsigned short a = __builtin_bit_cast(unsigned short, (__bf16)lo);
    unsigned short b = __builtin_bit_cast(unsigned short, (__bf16)hi);
    return (unsigned int)a | ((unsigned int)b << 16);
}

__global__ void sentinel_kernel(float* o) { o[threadIdx.x] = 1e9f; }

// ---------------------------------------------------------------------------
__global__ void transpose_w(const float* __restrict__ w, bf16_t* __restrict__ wt,
                            int K, int N)
{
    int i = blockIdx.x * 256 + threadIdx.x;
    if (i >= K * N) return;
    int k = i / N, n = i % N;
    wt[(long)n * K + k] = __float2bfloat16(w[i]);
}

// zero vT pad keys 49..55 for all (win, d)
__global__ void zpad_kernel(bf16_t* __restrict__ vT)
{
    long i = (long)blockIdx.x * 256 + threadIdx.x;
    if (i >= (long)NWIN * 128 * 7) return;
    long row = i / 7;
    int  k   = 49 + (int)(i % 7);
    vT[row * VSTR + k] = __float2bfloat16(0.f);
}

// ---------------------------------------------------------------------------
// GEMM, one wave = 64x64 output tile. Block = 4 waves stacked in M (256 rows).
// grid = (M/256, N/64).
// LNM: 0 = A is plain bf16 row-major
//      1 = A = LN1(gather shifted/windowed row of x f32)   [qkv]
// EPI: 0 = qkv: cols<256 -> qk[token][256]; cols>=256 -> vT[win][d][key]
//      1 = proj: window-reverse + unshift + x(f32) residual -> f32 out
// ---------------------------------------------------------------------------
template<int K, int N, int LNM, int EPI>
__global__ __launch_bounds__(256) void gemm2(const void*  __restrict__ Asrc,
                                             const float* __restrict__ lng,
                                             const float* __restrict__ lnb,
                                             const bf16_t* __restrict__ Bt,
                                             const float*  __restrict__ bias,
                                             void*         outp,
                                             const float*  resf,
                                             bf16_t*       vTp)
{
    int lane = threadIdx.x & 63;
    int wave = threadIdx.x >> 6;
    int la = lane & 15, lb = lane >> 4;
    int m0   = (blockIdx.x * 4 + wave) * 64;
    int c0   = blockIdx.y * 64;

    f32x4 acc[4][4];
#pragma unroll
    for (int nt = 0; nt < 4; ++nt) {
        float bv = bias[c0 + nt * 16 + la];
#pragma unroll
        for (int s = 0; s < 4; ++s) acc[s][nt] = (f32x4){bv, bv, bv, bv};
    }

    static_assert(K == 128, "gemm2 is K=128 only now");
    bf16x8 areg[4][4];
    if constexpr (LNM == 0) {
#pragma unroll
        for (int s = 0; s < 4; ++s)
#pragma unroll
            for (int kt = 0; kt < 4; ++kt)
                areg[s][kt] = *reinterpret_cast<const bf16x8*>(
                    (const bf16_t*)Asrc + (long)(m0 + s * 16 + la) * K + kt * 32 + lb * 8);
    } else {
#pragma unroll
        for (int s = 0; s < 4; ++s) {
            long src = win_to_tok(m0 + s * 16 + la);
            const float* xr = (const float*)Asrc + src * C_;
            float vals[4][8];
            float sm = 0.f, qs = 0.f;
#pragma unroll
            for (int kt = 0; kt < 4; ++kt) {
                f32x4 u0 = *reinterpret_cast<const f32x4*>(xr + kt * 32 + lb * 8);
                f32x4 u1 = *reinterpret_cast<const f32x4*>(xr + kt * 32 + lb * 8 + 4);
#pragma unroll
                for (int j = 0; j < 4; ++j) { vals[kt][j] = u0[j]; vals[kt][4 + j] = u1[j]; }
#pragma unroll
                for (int j = 0; j < 8; ++j) { sm += vals[kt][j]; qs += vals[kt][j] * vals[kt][j]; }
            }
            sm += __shfl_xor(sm, 16); sm += __shfl_xor(sm, 32);
            qs += __shfl_xor(qs, 16); qs += __shfl_xor(qs, 32);
            float mean = sm * (1.f / 128.f);
            float rstd = rsqrtf(qs * (1.f / 128.f) - mean * mean + 1e-5f);
#pragma unroll
            for (int kt = 0; kt < 4; ++kt)
#pragma unroll
                for (int j = 0; j < 8; ++j) {
                    int col = kt * 32 + lb * 8 + j;
                    areg[s][kt][j] = (__bf16)((vals[kt][j] - mean) * rstd * lng[col] + lnb[col]);
                }
        }
    }

    bf16x8 breg[4][4];
#pragma unroll
    for (int kt = 0; kt < 4; ++kt)
#pragma unroll
        for (int nt = 0; nt < 4; ++nt)
            breg[kt][nt] = *reinterpret_cast<const bf16x8*>(
                Bt + (long)(c0 + nt * 16 + la) * K + kt * 32 + lb * 8);
#pragma unroll
    for (int kt = 0; kt < 4; ++kt)
#pragma unroll
        for (int nt = 0; nt < 4; ++nt)
#pragma unroll
            for (int s = 0; s < 4; ++s)
                acc[s][nt] = __builtin_amdgcn_mfma_f32_16x16x32_bf16(
                    areg[s][kt], breg[kt][nt], acc[s][nt], 0, 0, 0);

#pragma unroll
    for (int s = 0; s < 4; ++s) {
#pragma unroll
        for (int r = 0; r < 4; ++r) {
            int row = m0 + s * 16 + lb * 4 + r;
            if constexpr (EPI == 0) {
                int win = row / 49, key = row - win * 49;
#pragma unroll
                for (int nt = 0; nt < 4; ++nt) {
                    int col = c0 + nt * 16 + la;
                    float v = acc[s][nt][r];
                    if (col < 256)
                        ((bf16_t*)outp)[(long)row * 256 + col] = __float2bfloat16(v);
                    else
                        vTp[((long)win * 128 + (col - 256)) * VSTR + key] = __float2bfloat16(v);
                }
            } else {
                long to = win_to_tok(row);
#pragma unroll
                for (int nt = 0; nt < 4; ++nt) {
                    int col = c0 + nt * 16 + la;
                    ((float*)outp)[to * C_ + col] = acc[s][nt][r] + resf[to * C_ + col];
                }
            }
        }
    }
}

// ---------------------------------------------------------------------------
// MFMA windowed attention: one block per window, one wave per head. No LDS.
// ---------------------------------------------------------------------------
__global__ __launch_bounds__(256) void attn_mfma(const bf16_t* __restrict__ qk,
                                                 const bf16_t* __restrict__ vT,
                                                 const float*  __restrict__ rpb,
                                                 bf16_t* __restrict__ out)
{
    int win  = blockIdx.x;
    int h    = threadIdx.x >> 6;
    int lane = threadIdx.x & 63;
    int la = lane & 15, lb = lane >> 4;

    const bf16_t* qkw = qk + (long)win * 49 * 256;

    bf16x8 kf[4], qf[4];
#pragma unroll
    for (int t = 0; t < 4; ++t) {
        kf[t] = *reinterpret_cast<const bf16x8*>(qkw + (long)(t * 16 + la) * 256 + 128 + h * 32 + lb * 8);
        qf[t] = *reinterpret_cast<const bf16x8*>(qkw + (long)(t * 16 + la) * 256 +       h * 32 + lb * 8);
    }

    f32x4 S[4][4];
#pragma unroll
    for (int qt = 0; qt < 4; ++qt)
#pragma unroll
        for (int kt = 0; kt < 4; ++kt)
            S[qt][kt] = __builtin_amdgcn_mfma_f32_16x16x32_bf16(
                kf[kt], qf[qt], (f32x4){0.f, 0.f, 0.f, 0.f}, 0, 0, 0);

    const float scale = 0.17677669529663687f;   // 1/sqrt(32)
    int wi  = win & 63;
    int wh  = wi >> 3, wwp = wi & 7;
    bool edge = (wh == 7) || (wwp == 7);

    int i1[4], j1[4], r1[4], c1[4];
#pragma unroll
    for (int qt = 0; qt < 4; ++qt) {
        int q  = qt * 16 + la;
        int qc = q < 49 ? q : 48;
        i1[qt] = qc / 7; j1[qt] = qc - 7 * i1[qt];
        r1[qt] = (wh  < 7) ? 0 : ((i1[qt] < 4) ? 1 : 2);
        c1[qt] = (wwp < 7) ? 0 : ((j1[qt] < 4) ? 1 : 2);
    }

#pragma unroll
    for (int kt = 0; kt < 4; ++kt) {
#pragma unroll
        for (int r = 0; r < 4; ++r) {
            if (kt == 3 && r > 0) {
#pragma unroll
                for (int qt = 0; qt < 4; ++qt) S[qt][kt][r] = -1e30f;
                continue;
            }
            int key = kt * 16 + lb * 4 + r;
            int kc  = key < 49 ? key : 48;
            int i2  = kc / 7, j2 = kc - 7 * i2;
            int r2  = (wh  < 7) ? 0 : ((i2 < 4) ? 1 : 2);
            int c2  = (wwp < 7) ? 0 : ((j2 < 4) ? 1 : 2);
#pragma unroll
            for (int qt = 0; qt < 4; ++qt) {
                float bv  = rpb[(((i1[qt] - i2 + 6) * 13 + (j1[qt] - j2 + 6)) << 2) + h];
                float val = S[qt][kt][r] * scale + bv;
                if (edge && ((r1[qt] != r2) | (c1[qt] != c2))) val -= 100.f;
                if (kt == 3 && lb > 0) val = -1e30f;
                S[qt][kt][r] = val;
            }
        }
    }

    float inv[4];
#pragma unroll
    for (int qt = 0; qt < 4; ++qt) {
        float mx = -3e38f;
#pragma unroll
        for (int kt = 0; kt < 4; ++kt)
#pragma unroll
            for (int r = 0; r < 4; ++r) mx = fmaxf(mx, S[qt][kt][r]);
        mx = fmaxf(mx, __shfl_xor(mx, 16));
        mx = fmaxf(mx, __shfl_xor(mx, 32));
        float sm = 0.f;
#pragma unroll
        for (int kt = 0; kt < 4; ++kt)
#pragma unroll
            for (int r = 0; r < 4; ++r) {
                float e = __expf(S[qt][kt][r] - mx);
                S[qt][kt][r] = e;
                sm += e;
            }
        sm += __shfl_xor(sm, 16);
        sm += __shfl_xor(sm, 32);
        inv[qt] = 1.f / sm;
    }

    unsigned int w_[4][4][2];
#pragma unroll
    for (int qt = 0; qt < 4; ++qt)
#pragma unroll
        for (int t = 0; t < 4; ++t) {
            w_[qt][t][0] = pk2(S[qt][t][0], S[qt][t][1]);
            w_[qt][t][1] = pk2(S[qt][t][2], S[qt][t][3]);
        }

    int srcA = la + (((2 * lb)     & 3) << 4);
    int srcB = la + (((2 * lb + 1) & 3) << 4);
    bool hiT = (lb >> 1) & 1;

    f32x4 O[2][4];
#pragma unroll
    for (int dt = 0; dt < 2; ++dt)
#pragma unroll
        for (int qt = 0; qt < 4; ++qt) O[dt][qt] = (f32x4){0.f, 0.f, 0.f, 0.f};

    const bf16_t* vrow = vT + ((long)win * 128 + h * 32) * VSTR;
#pragma unroll
    for (int kk = 0; kk < 2; ++kk) {
        bf16x8 vf[2];
#pragma unroll
        for (int dt = 0; dt < 2; ++dt)
            vf[dt] = *reinterpret_cast<const bf16x8*>(
                vrow + (long)(dt * 16 + la) * VSTR + kk * 32 + lb * 8);
        int tl = kk * 2;
#pragma unroll
        for (int qt = 0; qt < 4; ++qt) {
            unsigned int a0 = __shfl(w_[qt][tl][0],     srcA);
            unsigned int b0 = __shfl(w_[qt][tl + 1][0], srcA);
            unsigned int a1 = __shfl(w_[qt][tl][1],     srcA);
            unsigned int b1 = __shfl(w_[qt][tl + 1][1], srcA);
            unsigned int a2 = __shfl(w_[qt][tl][0],     srcB);
            unsigned int b2 = __shfl(w_[qt][tl + 1][0], srcB);
            unsigned int a3 = __shfl(w_[qt][tl][1],     srcB);
            unsigned int b3 = __shfl(w_[qt][tl + 1][1], srcB);
            u32x4 uu = { hiT ? b0 : a0, hiT ? b1 : a1, hiT ? b2 : a2, hiT ? b3 : a3 };
            bf16x8 pf = __builtin_bit_cast(bf16x8, uu);
#pragma unroll
            for (int dt = 0; dt < 2; ++dt)
                O[dt][qt] = __builtin_amdgcn_mfma_f32_16x16x32_bf16(vf[dt], pf, O[dt][qt], 0, 0, 0);
        }
    }

    bf16_t* ob = out + (long)win * 49 * C_ + h * 32;
#pragma unroll
    for (int qt = 0; qt < 4; ++qt) {
        int q = qt * 16 + la;
        if (q < 49) {
            float iv = inv[qt];
#pragma unroll
            for (int dt = 0; dt < 2; ++dt) {
                unsigned int s0 = pk2(O[dt][qt][0] * iv, O[dt][qt][1] * iv);
                unsigned int s1 = pk2(O[dt][qt][2] * iv, O[dt][qt][3] * iv);
                uint2 st = {s0, s1};
                *reinterpret_cast<uint2*>(ob + (long)q * C_ + dt * 16 + lb * 4) = st;
            }
        }
    }
}

// ---------------------------------------------------------------------------
// Fused MLP v3: out = y + fc2(gelu(fc1(LN2(y)))).  One wave = 32 rows.
// No LDS, no barriers. fc1 computed TRANSPOSED: hT = mfma(A=W1t rows, B=af)
// so hT[n1 = c*64+nt*16+lb*4+r][m = s*16+la] — hidden in (nt, lb*4+r), m in
// la: exactly the attention repack source layout (key<->hidden, q<->m).
// The verified attention shuffle then builds fc2's B-fragments; A = W2t rows.
// ---------------------------------------------------------------------------
__global__ __launch_bounds__(256) void mlp_fused(const float* __restrict__ y,
                                                 const float* __restrict__ g,
                                                 const float* __restrict__ b,
                                                 const bf16_t* __restrict__ w1t,
                                                 const float* __restrict__ b1,
                                                 const bf16_t* __restrict__ w2t,
                                                 const float* __restrict__ b2,
                                                 float* __restrict__ out)
{
    int lane = threadIdx.x & 63;
    int la = lane & 15, lb = lane >> 4;
    int m0 = (blockIdx.x * 4 + (threadIdx.x >> 6)) * 32;

    // ---- LN2 -> fragments for 2 row-subtiles (m = s*16+la, k = kt*32+lb*8+j)
    bf16x8 af[2][4];
#pragma unroll
    for (int s = 0; s < 2; ++s) {
        const float* yr = y + (long)(m0 + s * 16 + la) * C_;
        float vals[4][8];
        float sm = 0.f, qs = 0.f;
#pragma unroll
        for (int kt = 0; kt < 4; ++kt) {
            f32x4 u0 = *reinterpret_cast<const f32x4*>(yr + kt * 32 + lb * 8);
            f32x4 u1 = *reinterpret_cast<const f32x4*>(yr + kt * 32 + lb * 8 + 4);
#pragma unroll
            for (int j = 0; j < 4; ++j) { vals[kt][j] = u0[j]; vals[kt][4 + j] = u1[j]; }
#pragma unroll
            for (int j = 0; j < 8; ++j) { sm += vals[kt][j]; qs += vals[kt][j] * vals[kt][j]; }
        }
        sm += __shfl_xor(sm, 16); sm += __shfl_xor(sm, 32);
        qs += __shfl_xor(qs, 16); qs += __shfl_xor(qs, 32);
        float mean = sm * (1.f / 128.f);
        float rstd = rsqrtf(qs * (1.f / 128.f) - mean * mean + 1e-5f);
#pragma unroll
        for (int kt = 0; kt < 4; ++kt)
#pragma unroll
            for (int j = 0; j < 8; ++j) {
                int col = kt * 32 + lb * 8 + j;
                af[s][kt][j] = (__bf16)((vals[kt][j] - mean) * rstd * g[col] + b[col]);
            }
    }

    // ---- out^T accumulators: acc[s][nt2]: out[m=s*16+la][n2=nt2*16+lb*4+r]
    f32x4 acc[2][8];
#pragma unroll
    for (int nt2 = 0; nt2 < 8; ++nt2) {
        f32x4 bv = *reinterpret_cast<const f32x4*>(b2 + nt2 * 16 + lb * 4);
#pragma unroll
        for (int s = 0; s < 2; ++s) acc[s][nt2] = bv;
    }

    int srcA = la + (((2 * lb)     & 3) << 4);
    int srcB = la + (((2 * lb + 1) & 3) << 4);
    bool hiT = (lb >> 1) & 1;

    for (int c = 0; c < 8; ++c) {
        // ---- fc1 chunk TRANSPOSED: hT[n1][m], n1 = c*64+nt*16+lb*4+r, m = s*16+la
        f32x4 hacc[2][4];
#pragma unroll
        for (int nt = 0; nt < 4; ++nt) {
            f32x4 bv = *reinterpret_cast<const f32x4*>(b1 + c * 64 + nt * 16 + lb * 4);
#pragma unroll
            for (int s = 0; s < 2; ++s) hacc[s][nt] = bv;
        }
#pragma unroll
        for (int kt = 0; kt < 4; ++kt)
#pragma unroll
            for (int nt = 0; nt < 4; ++nt) {
                bf16x8 w1f = *reinterpret_cast<const bf16x8*>(
                    w1t + (long)(c * 64 + nt * 16 + la) * 128 + kt * 32 + lb * 8);
#pragma unroll
                for (int s = 0; s < 2; ++s)
                    hacc[s][nt] = __builtin_amdgcn_mfma_f32_16x16x32_bf16(
                        w1f, af[s][kt], hacc[s][nt], 0, 0, 0);
            }
        // ---- exact GELU + pack to bf16 pairs (hidden pairs along r) ----
        unsigned int wpk[2][4][2];
#pragma unroll
        for (int s = 0; s < 2; ++s)
#pragma unroll
            for (int t = 0; t < 4; ++t) {
                f32x4 hv = hacc[s][t];
#pragma unroll
                for (int r = 0; r < 4; ++r)
                    hv[r] = 0.5f * hv[r] * (1.f + erff(hv[r] * 0.70710678118654752f));
                wpk[s][t][0] = pk2(hv[0], hv[1]);
                wpk[s][t][1] = pk2(hv[2], hv[3]);
            }
        // ---- fc2 chunk: acc[s][nt2] += mfma(W2t rows, hT B-frag) ----
#pragma unroll
        for (int kk = 0; kk < 2; ++kk) {
            bf16x8 w2f[8];
#pragma unroll
            for (int nt2 = 0; nt2 < 8; ++nt2)
                w2f[nt2] = *reinterpret_cast<const bf16x8*>(
                    w2t + (long)(nt2 * 16 + la) * 512 + c * 64 + kk * 32 + lb * 8);
            int tl = kk * 2;
#pragma unroll
            for (int s = 0; s < 2; ++s) {
                unsigned int a0 = __shfl(wpk[s][tl][0],     srcA);
                unsigned int b0 = __shfl(wpk[s][tl + 1][0], srcA);
                unsigned int a1 = __shfl(wpk[s][tl][1],     srcA);
                unsigned int b1v = __shfl(wpk[s][tl + 1][1], srcA);
                unsigned int a2 = __shfl(wpk[s][tl][0],     srcB);
                unsigned int b2v = __shfl(wpk[s][tl + 1][0], srcB);
                unsigned int a3 = __shfl(wpk[s][tl][1],     srcB);
                unsigned int b3v = __shfl(wpk[s][tl + 1][1], srcB);
                u32x4 uu = { hiT ? b0 : a0, hiT ? b1v : a1, hiT ? b2v : a2, hiT ? b3v : a3 };
                bf16x8 pf = __builtin_bit_cast(bf16x8, uu);
#pragma unroll
                for (int nt2 = 0; nt2 < 8; ++nt2)
                    acc[s][nt2] = __builtin_amdgcn_mfma_f32_16x16x32_bf16(
                        w2f[nt2], pf, acc[s][nt2], 0, 0, 0);
            }
        }
    }

    // ---- epilogue: + y residual -> out (in-place safe: exclusive rows) ----
#pragma unroll
    for (int s = 0; s < 2; ++s) {
        long m = m0 + s * 16 + la;
        const float* yrow = y + m * C_;
        float* orow = out + m * C_;
#pragma unroll
        for (int nt2 = 0; nt2 < 8; ++nt2) {
            int n2 = nt2 * 16 + lb * 4;
            f32x4 res = *reinterpret_cast<const f32x4*>(yrow + n2);
            f32x4 val = acc[s][nt2] + res;
            *reinterpret_cast<f32x4*>(orow + n2) = val;
        }
    }
}

// ---------------------------------------------------------------------------
extern "C" void kernel_launch(void* const* d_in, const int* in_sizes, int n_in,
                              void* d_out, int out_size, void* d_ws, size_t ws_size,
                              hipStream_t stream)
{
    (void)in_sizes; (void)n_in; (void)out_size;

    const float* x      = (const float*)d_in[0];
    const float* n1g    = (const float*)d_in[1];
    const float* n1b    = (const float*)d_in[2];
    const float* qkv_w  = (const float*)d_in[3];
    const float* qkv_b  = (const float*)d_in[4];
    const float* proj_w = (const float*)d_in[5];
    const float* proj_b = (const float*)d_in[6];
    const float* rpb    = (const float*)d_in[7];
    const float* n2g    = (const float*)d_in[8];
    const float* n2b    = (const float*)d_in[9];
    const float* fc1_w  = (const float*)d_in[10];
    const float* fc1_b  = (const float*)d_in[11];
    const float* fc2_w  = (const float*)d_in[12];
    const float* fc2_b  = (const float*)d_in[13];

    char* ws = (char*)d_ws;

    const size_t qk_sz = (size_t)M_ * 256 * 2;               // 102,760,448
    const size_t vt_sz = (size_t)NWIN * 128 * VSTR * 2;      //  58,720,256
    const size_t at_sz = (size_t)M_ * 128 * 2;               //  51,380,224
    const size_t w_off = qk_sz + vt_sz + at_sz;
    const size_t w_sz  = (size_t)(128 * 384 + 128 * 128 + 128 * 512 + 512 * 128) * 2;
    const size_t need  = w_off + w_sz;                       // ~213.6 MB

    if (need > ws_size) {
        sentinel_kernel<<<1, 256, 0, stream>>>((float*)d_out);
        return;
    }

    bf16_t* qkb  = (bf16_t*)ws;
    bf16_t* vT   = (bf16_t*)(ws + qk_sz);
    bf16_t* attb = (bf16_t*)(ws + qk_sz + vt_sz);
    bf16_t* qkv_wt  = (bf16_t*)(ws + w_off);
    bf16_t* proj_wt = qkv_wt + 128 * 384;
    bf16_t* fc1_wt  = proj_wt + 128 * 128;
    bf16_t* fc2_wt  = fc1_wt + 128 * 512;

    float* y = (float*)d_out;

    transpose_w<<<(128 * 384 + 255) / 256, 256, 0, stream>>>(qkv_w, qkv_wt, 128, 384);
    transpose_w<<<(128 * 128 + 255) / 256, 256, 0, stream>>>(proj_w, proj_wt, 128, 128);
    transpose_w<<<(128 * 512 + 255) / 256, 256, 0, stream>>>(fc1_w, fc1_wt, 128, 512);
    transpose_w<<<(512 * 128 + 255) / 256, 256, 0, stream>>>(fc2_w, fc2_wt, 512, 128);

    // zero vT pad keys (NaN safety for PV fragments)
    zpad_kernel<<<(NWIN * 128 * 7 + 255) / 256, 256, 0, stream>>>(vT);
    // LN1 + shift/window gather fused into QKV projection
    gemm2<128, 384, 1, 0><<<dim3(M_ / 256, 6), 256, 0, stream>>>(
        x, n1g, n1b, qkv_wt, qkv_b, qkb, nullptr, vT);
    // MFMA attention
    attn_mfma<<<NWIN, 256, 0, stream>>>(qkb, vT, rpb, attb);
    // proj + window-reverse + x residual -> f32 y (= d_out)
    gemm2<128, 128, 0, 1><<<dim3(M_ / 256, 2), 256, 0, stream>>>(
        attb, nullptr, nullptr, proj_wt, proj_b, y, x, nullptr);
    // fused LN2 + fc1 + GELU + fc2 + residual (in-place on d_out, no LDS)
    mlp_fused<<<M_ / 128, 256, 0, stream>>>(
        y, n2g, n2b, fc1_wt, fc1_b, fc2_wt, fc2_b, y);
}